// Round 3
// baseline (571.218 us; speedup 1.0000x reference)
//
#include <hip/hip_runtime.h>
#include <hip/hip_bf16.h>

// SpMM: out[row[e], :] += values[e] * b[col[e], :]
// N=100000, E=3200000, D=64, fp32.
// Round 2: counting-sort -> CSR -> one wave per row.
//   - spmm inner loop batched x8 (8 gathers in flight; round 1 had ~1,
//     VALUBusy 22%, latency-bound).
//   - scatter: cursors pre-initialized to offsets (drops random offsets[r]
//     read); 4 edges/thread via int4/float4.
//   - hist: 4 edges/thread.

#define D 64

// ---------------- fallback (round-0) path, used only if ws too small -------
__global__ __launch_bounds__(256) void spmm_atomic_kernel(
    const int* __restrict__ rows, const int* __restrict__ cols,
    const float* __restrict__ vals, const float* __restrict__ b,
    float* __restrict__ out, int E) {
  long long gid = (long long)blockIdx.x * blockDim.x + threadIdx.x;
  int e = (int)(gid >> 6);
  int d = (int)(gid & 63);
  if (e >= E) return;
  int r = rows[e];
  int c = cols[e];
  float v = vals[e];
  atomicAdd(&out[(long long)r * D + d], v * b[(long long)c * D + d]);
}

// ---------------- pass 1: histogram of rows (4 edges/thread) ---------------
__global__ __launch_bounds__(256) void hist_kernel(
    const int* __restrict__ rows, int* __restrict__ counts, int E) {
  int i = blockIdx.x * blockDim.x + threadIdx.x;
  int e0 = i * 4;
  if (e0 + 3 < E) {
    int4 r = *(const int4*)(rows + e0);
    atomicAdd(&counts[r.x], 1);
    atomicAdd(&counts[r.y], 1);
    atomicAdd(&counts[r.z], 1);
    atomicAdd(&counts[r.w], 1);
  } else {
    for (int e = e0; e < E; e++) atomicAdd(&counts[rows[e]], 1);
  }
}

// ---------------- pass 2: two-level exclusive scan over counts -------------
__global__ __launch_bounds__(512) void scan_blocks_kernel(
    const int* __restrict__ counts, int* __restrict__ incl,
    int* __restrict__ bsums, int n) {
  __shared__ int s[512];
  int i = blockIdx.x * 512 + threadIdx.x;
  int v = (i < n) ? counts[i] : 0;
  s[threadIdx.x] = v;
  __syncthreads();
  for (int off = 1; off < 512; off <<= 1) {
    int t = (threadIdx.x >= (unsigned)off) ? s[threadIdx.x - off] : 0;
    __syncthreads();
    s[threadIdx.x] += t;
    __syncthreads();
  }
  if (i < n) incl[i] = s[threadIdx.x];
  if (threadIdx.x == 511) bsums[blockIdx.x] = s[511];
}

__global__ __launch_bounds__(256) void scan_sums_kernel(
    int* __restrict__ bsums, int nb) {
  __shared__ int s[256];
  int v = (threadIdx.x < (unsigned)nb) ? bsums[threadIdx.x] : 0;
  s[threadIdx.x] = v;
  __syncthreads();
  for (int off = 1; off < 256; off <<= 1) {
    int t = (threadIdx.x >= (unsigned)off) ? s[threadIdx.x - off] : 0;
    __syncthreads();
    s[threadIdx.x] += t;
    __syncthreads();
  }
  if (threadIdx.x < (unsigned)nb) bsums[threadIdx.x] = s[threadIdx.x] - v;
}

// offsets[i] = incl[i] - counts[i] + bsums[chunk]; cursors[i] = offsets[i]
__global__ __launch_bounds__(256) void finalize_offsets_kernel(
    const int* __restrict__ incl, const int* __restrict__ counts,
    const int* __restrict__ bsums, int* __restrict__ offsets,
    int* __restrict__ cursors, int n) {
  int i = blockIdx.x * blockDim.x + threadIdx.x;
  if (i < n) {
    int o = incl[i] - counts[i] + bsums[i >> 9];
    offsets[i] = o;
    cursors[i] = o;
  }
}

// ---------------- pass 3: scatter edges into row-sorted order --------------
__global__ __launch_bounds__(256) void scatter_kernel(
    const int* __restrict__ rows, const int* __restrict__ cols,
    const float* __restrict__ vals, int* __restrict__ cursors,
    float2* __restrict__ pairs, int E) {
  int i = blockIdx.x * blockDim.x + threadIdx.x;
  int e0 = i * 4;
  if (e0 + 3 < E) {
    int4 r = *(const int4*)(rows + e0);
    int4 c = *(const int4*)(cols + e0);
    float4 v = *(const float4*)(vals + e0);
    int p0 = atomicAdd(&cursors[r.x], 1);
    int p1 = atomicAdd(&cursors[r.y], 1);
    int p2 = atomicAdd(&cursors[r.z], 1);
    int p3 = atomicAdd(&cursors[r.w], 1);
    pairs[p0] = make_float2(__int_as_float(c.x), v.x);
    pairs[p1] = make_float2(__int_as_float(c.y), v.y);
    pairs[p2] = make_float2(__int_as_float(c.z), v.z);
    pairs[p3] = make_float2(__int_as_float(c.w), v.w);
  } else {
    for (int e = e0; e < E; e++) {
      int pos = atomicAdd(&cursors[rows[e]], 1);
      pairs[pos] = make_float2(__int_as_float(cols[e]), vals[e]);
    }
  }
}

// ---------------- pass 4: CSR SpMM, one wave per row, 8-batched ILP --------
__global__ __launch_bounds__(256) void spmm_csr_kernel(
    const float2* __restrict__ pairs, const int* __restrict__ offsets,
    const int* __restrict__ counts, const float* __restrict__ b,
    float* __restrict__ out, int N) {
  int t = blockIdx.x * blockDim.x + threadIdx.x;
  int w = t >> 6;   // row
  int d = t & 63;   // output column (lane)
  if (w >= N) return;
  int start = offsets[w];
  int cnt = counts[w];
  float acc = 0.f;
  for (int base = 0; base < cnt; base += 64) {
    int m = cnt - base;
    if (m > 64) m = 64;
    // cooperative load: lane d grabs edge (base+d). Lanes >= m carry
    // (c=0, v=0): the padded gathers hit b[0..63] (valid, L1-hot), FMA adds 0.
    float2 p = (d < m) ? pairs[start + base + d] : make_float2(0.f, 0.f);
    int pc = __float_as_int(p.x);
    float pv = p.y;
    int mr = (m + 7) & ~7;  // round up to batch of 8, no divergent remainder
    for (int j = 0; j < mr; j += 8) {
      float vv[8], bv[8];
#pragma unroll
      for (int k = 0; k < 8; k++) {
        int c = __shfl(pc, j + k);
        vv[k] = __shfl(pv, j + k);
        bv[k] = b[(long long)c * D + d];   // 8 independent gathers in flight
      }
#pragma unroll
      for (int k = 0; k < 8; k++) acc += vv[k] * bv[k];
    }
  }
  out[(long long)w * D + d] = acc;  // single coalesced store, no atomics
}

extern "C" void kernel_launch(void* const* d_in, const int* in_sizes, int n_in,
                              void* d_out, int out_size, void* d_ws, size_t ws_size,
                              hipStream_t stream) {
  const int* indices = (const int*)d_in[0];   // (2, E) int32
  const float* vals  = (const float*)d_in[1]; // (E,)
  const float* b     = (const float*)d_in[3]; // (N, D)

  int E = in_sizes[1];
  int N = in_sizes[3] / D;
  const int* rows = indices;
  const int* cols = indices + E;

  int nblocks_scan = (N + 511) / 512;

  // workspace layout
  size_t off_counts  = 0;
  size_t off_cursors = off_counts  + (size_t)N * 4;
  size_t off_offsets = off_cursors + (size_t)N * 4;
  size_t off_incl    = off_offsets + (size_t)N * 4;
  size_t off_bsums   = off_incl    + (size_t)N * 4;
  size_t off_pairs   = (off_bsums + 256 * 4 + 15) & ~(size_t)15;
  size_t need        = off_pairs + (size_t)E * 8;

  if (ws_size < need || nblocks_scan > 256) {
    hipMemsetAsync(d_out, 0, (size_t)out_size * sizeof(float), stream);
    long long total = (long long)E * 64;
    spmm_atomic_kernel<<<(int)((total + 255) / 256), 256, 0, stream>>>(
        rows, cols, vals, b, (float*)d_out, E);
    return;
  }

  char* ws = (char*)d_ws;
  int*    counts  = (int*)(ws + off_counts);
  int*    cursors = (int*)(ws + off_cursors);
  int*    offsets = (int*)(ws + off_offsets);
  int*    incl    = (int*)(ws + off_incl);
  int*    bsums   = (int*)(ws + off_bsums);
  float2* pairs   = (float2*)(ws + off_pairs);

  // zero counts only (cursors initialized by finalize)
  hipMemsetAsync(counts, 0, (size_t)N * 4, stream);

  int E4 = (E + 3) / 4;
  hist_kernel<<<(E4 + 255) / 256, 256, 0, stream>>>(rows, counts, E);
  scan_blocks_kernel<<<nblocks_scan, 512, 0, stream>>>(counts, incl, bsums, N);
  scan_sums_kernel<<<1, 256, 0, stream>>>(bsums, nblocks_scan);
  finalize_offsets_kernel<<<(N + 255) / 256, 256, 0, stream>>>(
      incl, counts, bsums, offsets, cursors, N);
  scatter_kernel<<<(E4 + 255) / 256, 256, 0, stream>>>(
      rows, cols, vals, cursors, pairs, E);
  spmm_csr_kernel<<<(int)(((long long)N * 64 + 255) / 256), 256, 0, stream>>>(
      pairs, offsets, counts, b, (float*)d_out, N);
}